// Round 11
// baseline (201.217 us; speedup 1.0000x reference)
//
#include <hip/hip_runtime.h>
#include <hip/hip_fp16.h>

#define NATOMS 768
#define NM1    767
#define NEDGE  (768*767)       // 589056
#define DIM    64
#define NC     50
#define GAPF   (5.0f/49.0f)
#define NIGAP  (-49.0f/5.0f)
// readout table (exact, paired): G=512
#define G      512
#define STEPF  (5.0f/511.0f)
#define INVSTEP (511.0f/5.0f)
// conv tables: G2=256 UNPAIRED f16 (32 KB/layer -> LDS-resident at 4 blocks/CU)
#define G2      256
#define STEPC   (5.0f/255.0f)
#define INVSTEPC (255.0f/5.0f)
#define LN2F   0.693147180559945f

// ws layout (float offsets)
#define WS_H     0              // 768*64 f32
#define WS_NWA   49152          // 768*64 f16 ROW-MAJOR: nw[i*64+c]
#define WS_NWB   73728          // 768*64 f16 row-major
#define WS_HA    98304          // 768 f32 (+pad)
#define WS_DISTT 99328          // 768*768 f32
#define WS_TTC   689152         // 3 conv tables * 256*64 f16 (unpaired) = 24576 floats
#define WS_TTR   713728         // ro table 512*64 half2 (paired) = 32768 floats

__device__ __forceinline__ float softplus05(float x) {
    float bx = 0.5f * x;
    return (bx > 14.0f) ? x : 2.0f * __logf(1.0f + __expf(bx));
}
__device__ __forceinline__ int lane_bcast_i(int v, int l) {
    return __builtin_amdgcn_readlane(v, l);
}
__device__ __forceinline__ float lane_bcast_f(float v, int l) {
    return __uint_as_float((unsigned)__builtin_amdgcn_readlane((int)__float_as_uint(v), l));
}
__device__ __forceinline__ float2 pair2f(unsigned p) {
    __half2 h = *reinterpret_cast<__half2*>(&p);
    return __half22float2(h);
}

// ============ prologue ============
// grid 656: [0,192)   conv tables G2=256 UNPAIRED (w=b*4+widx in [0,768), tbl=w>>8, g=w&255)
//           [192,320) ro table G=512 paired
//           [320,512) embedding + nw0 (row-major f16)
//           [512,656) 64x64 tiled transpose dist -> distT
__global__ __launch_bounds__(256)
void k_pre(const int* __restrict__ types, const float* __restrict__ dist,
           const float* __restrict__ emb, const float* __restrict__ w1all,
           const float* __restrict__ pw1, const float* __restrict__ pb1,
           const float* __restrict__ pw2, const float* __restrict__ pb2,
           const float* __restrict__ row1, const float* __restrict__ rob1,
           float* __restrict__ ws) {
    __shared__ float s_t[4 * 64];
    __shared__ float s_tile[64][65];
    const int tid = threadIdx.x, widx = tid >> 6, c = tid & 63;
    float*  h     = ws + WS_H;
    __half* nwh   = (__half*)(ws + WS_NWA);
    float*  distT = ws + WS_DISTT;
    __half* TTCh  = (__half*)(ws + WS_TTC);
    __half* TTRh  = (__half*)(ws + WS_TTR);
    const int b = blockIdx.x;

    if (b < 192) {
        // conv tables, G2 = 256, UNPAIRED: TTC[tbl][g][c]
        const int w = b * 4 + widx, tbl = w >> 8, g = w & 255;
        const float d = g * STEPC;
        const float* W1 = pw1 + tbl * NC * DIM;
        float t1 = pb1[tbl * DIM + c];
        for (int k = 0; k < NC; ++k) {
            float x = d - GAPF * (float)k;
            t1 = fmaf(__expf(NIGAP * x * x), W1[k * DIM + c], t1);
        }
        s_t[widx * 64 + c] = softplus05(t1);         // wave-local lockstep
        const float* W2 = pw2 + tbl * DIM * DIM;
        float val = pb2[tbl * DIM + c];
        #pragma unroll 8
        for (int k = 0; k < DIM; ++k)
            val = fmaf(s_t[widx * 64 + k], W2[k * DIM + c], val);
        TTCh[tbl * (G2 * DIM) + g * DIM + c] = __float2half(val);
    } else if (b < 320) {
        // readout table, G = 512, paired (exact path, unchanged math)
        const int g = (b - 192) * 4 + widx;
        const float d = g * STEPF;
        float val = rob1[c];
        for (int k = 0; k < NC; ++k) {
            float x = d - GAPF * (float)k;
            val = fmaf(__expf(NIGAP * x * x), row1[(2 + k) * DIM + c], val);
        }
        TTRh[(g * DIM + c) * 2] = __float2half(val);
        if (g > 0) TTRh[((g - 1) * DIM + c) * 2 + 1] = __float2half(val);
    } else if (b < 512) {
        const int i = (b - 320) * 4 + widx;
        float hv = emb[types[i] * DIM + c];
        h[i * DIM + c] = hv;
        s_t[widx * 64 + c] = hv;                     // wave-local
        float acc = 0.0f;
        #pragma unroll 8
        for (int k = 0; k < DIM; ++k)
            acc = fmaf(s_t[widx * 64 + k], w1all[k * DIM + c], acc);
        nwh[i * 64 + c] = __float2half(acc);         // row-major
    } else {
        // ---- coalesced tiled transpose: dist(i-major, edge order) -> distT[j][i]
        const int t = b - 512;                       // 144 tiles = 12 x 12
        const int I0 = (t / 12) * 64, J0 = (t % 12) * 64;
        #pragma unroll 4
        for (int r = 0; r < 16; ++r) {               // read rows of dist, coalesced in j
            const int i = I0 + widx * 16 + r;
            const int j = J0 + c;
            s_tile[widx * 16 + r][c] =
                (i == j) ? 0.0f : dist[i * NM1 + (j - (j > i))];
        }
        __syncthreads();
        #pragma unroll 4
        for (int r = 0; r < 16; ++r) {               // write rows of distT, coalesced in i
            const int j = J0 + widx * 16 + r;
            const int i = I0 + c;
            distT[j * NATOMS + i] = s_tile[c][widx * 16 + r];
        }
    }
}

// ============ conv layer: LDS-resident 32KB table at FULL occupancy ============
// 768 blocks x 8 waves; launch_bounds(512,8) -> VGPR<=64 -> 4 blocks/CU = 2048 thr.
// Lane c owns channels 2*(c&31), 2*(c&31)+1 of source-half (c>>5).
// Table reads: 2x ds_read_b32 (rows g, g+1), banks = cl -> 2-way alias (free).
// Only nw remains a global load (1 dword per source-pair per lane).
__global__ __launch_bounds__(512, 8)
void k_edgeupd(const __half* __restrict__ TTl, const float* __restrict__ distT,
               const __half* __restrict__ nwin,
               const float* __restrict__ qw1, const float* __restrict__ qb1,
               const float* __restrict__ qw2, const float* __restrict__ qb2,
               float* __restrict__ h,
               const float* __restrict__ wnext, __half* __restrict__ nwout,
               const float* __restrict__ auw1, const float* __restrict__ aub1,
               const float* __restrict__ auw2, const float* __restrict__ aub2,
               float* __restrict__ ha, int last) {
    __shared__ unsigned s_tab[G2 * 32];              // 256 rows x 32 dwords = 32 KB
    __shared__ float s_part[8][64];
    __shared__ float s_upd[192];
    const int tid = threadIdx.x, widx = tid >> 6, c = tid & 63;
    const int j = blockIdx.x;
    const int s0 = widx * 96;
    const int half = c >> 5, cl = c & 31;

    { // ---- stage the 32 KB table into LDS (4 x uint4 per thread) ----
        const uint4* src = (const uint4*)TTl;
        uint4* dst = (uint4*)s_tab;
        #pragma unroll
        for (int it = 0; it < 4; ++it)
            dst[tid + it * 512] = src[tid + it * 512];
    }
    __syncthreads();

    const unsigned* tabl = s_tab + cl;               // lane's dword column
    const char* nwb = (const char*)nwin + half * 128 + cl * 4;
    float2 csum = make_float2(0.0f, 0.0f);
    { // ---- chunk A: sources s0 .. s0+63 (32 pairs); lane c holds (g,f) of s0+c
        float pos = distT[j * NATOMS + s0 + c] * INVSTEPC;
        int g = (int)pos;
        g = (g < 0) ? 0 : ((g > 254) ? 254 : g);
        float f = pos - (float)g;
        int kw = g * 32;                             // dword index of row g
        const char* nwrow = nwb + s0 * 128;
        #pragma unroll 8
        for (int t = 0; t < 32; ++t) {
            int kw0 = lane_bcast_i(kw, 2 * t);
            int kw1 = lane_bcast_i(kw, 2 * t + 1);
            float f0 = lane_bcast_f(f, 2 * t);
            float f1 = lane_bcast_f(f, 2 * t + 1);
            int kws = half ? kw1 : kw0;
            float fs = half ? f1 : f0;
            float2 lo = pair2f(tabl[kws]);           // (T[g][ch0], T[g][ch1])
            float2 hi = pair2f(tabl[kws + 32]);      // (T[g+1][ch0], T[g+1][ch1])
            float2 nwf = pair2f(*(const unsigned*)(nwrow + t * 256));
            float e0 = fmaf(fs, hi.x - lo.x, lo.x);
            float e1 = fmaf(fs, hi.y - lo.y, lo.y);
            csum.x = fmaf(e0, nwf.x, csum.x);
            csum.y = fmaf(e1, nwf.y, csum.y);
        }
    }
    { // ---- chunk B: sources s0+64 .. s0+95 (16 pairs); lanes mirrored via c&31
        float pos = distT[j * NATOMS + s0 + 64 + cl] * INVSTEPC;
        int g = (int)pos;
        g = (g < 0) ? 0 : ((g > 254) ? 254 : g);
        float f = pos - (float)g;
        int kw = g * 32;
        const char* nwrow = nwb + (s0 + 64) * 128;
        #pragma unroll 8
        for (int t = 0; t < 16; ++t) {
            int kw0 = lane_bcast_i(kw, 2 * t);
            int kw1 = lane_bcast_i(kw, 2 * t + 1);
            float f0 = lane_bcast_f(f, 2 * t);
            float f1 = lane_bcast_f(f, 2 * t + 1);
            int kws = half ? kw1 : kw0;
            float fs = half ? f1 : f0;
            float2 lo = pair2f(tabl[kws]);
            float2 hi = pair2f(tabl[kws + 32]);
            float2 nwf = pair2f(*(const unsigned*)(nwrow + t * 256));
            float e0 = fmaf(fs, hi.x - lo.x, lo.x);
            float e1 = fmaf(fs, hi.y - lo.y, lo.y);
            csum.x = fmaf(e0, nwf.x, csum.x);
            csum.y = fmaf(e1, nwf.y, csum.y);
        }
    }
    // combine even/odd source halves and repack to channel-per-slot
    float2 tot2;
    tot2.x = csum.x + __shfl_xor(csum.x, 32, 64);
    tot2.y = csum.y + __shfl_xor(csum.y, 32, 64);
    if (half == 0) *(float2*)&s_part[widx][2 * cl] = tot2;
    __syncthreads();

    if (widx == 0) {
        float tot = 0.0f;
        #pragma unroll
        for (int w8 = 0; w8 < 8; ++w8) tot += s_part[w8][c];
        // remove fake i==j term: distT diag=0 -> g=0,f=0 -> e = T[0][c] exactly
        float t0 = __half2float(((const __half*)s_tab)[c]);
        float nwj = __half2float(nwin[j * 64 + c]);
        tot -= t0 * nwj;
        // node MLP (wave-local LDS, lockstep)
        s_upd[c] = tot;
        float t = qb1[c];
        #pragma unroll 8
        for (int k = 0; k < DIM; ++k) t = fmaf(s_upd[k], qw1[k * DIM + c], t);
        s_upd[64 + c] = softplus05(t);
        float o = qb2[c];
        #pragma unroll 8
        for (int k = 0; k < DIM; ++k) o = fmaf(s_upd[64 + k], qw2[k * DIM + c], o);
        float hn = h[j * DIM + c] + o;
        h[j * DIM + c] = hn;
        s_upd[128 + c] = hn;
        if (!last) {
            float v = 0.0f;
            #pragma unroll 8
            for (int k = 0; k < DIM; ++k) v = fmaf(s_upd[128 + k], wnext[k * DIM + c], v);
            nwout[j * 64 + c] = __float2half(v);     // row-major
        } else {
            float t2 = aub1[c];
            #pragma unroll 8
            for (int k = 0; k < DIM; ++k) t2 = fmaf(s_upd[128 + k], auw1[k * DIM + c], t2);
            t2 = ((t2 > 20.0f) ? t2 : __logf(1.0f + __expf(t2))) - LN2F;
            float v = t2 * auw2[c];
            #pragma unroll
            for (int s = 32; s > 0; s >>= 1) v += __shfl_down(v, s, 64);
            if (c == 0) ha[j] = v + aub2[0];
        }
    }
}

// ============ readout: staged batch loads; src/dst by exact magic division ====
__global__ __launch_bounds__(256)
void k_ro(const float* __restrict__ dist, const float* __restrict__ ha,
          const __half2* __restrict__ TTro,
          const float* __restrict__ row1, const float* __restrict__ row2,
          const float* __restrict__ rob2, float* __restrict__ out) {
    __shared__ float s_h[4][16 * 65];
    __shared__ float s_w2[128];
    const int tid = threadIdx.x, widx = tid >> 6, c = tid & 63;
    if (tid < 128) s_w2[tid] = row2[tid];
    __syncthreads();
    const int ebase = (blockIdx.x * 4 + widx) * 64;

    // lane c holds the params of edge ebase+c, in registers
    int kxv; float ff, fa, fb;
    {
        int eg = ebase + c;
        float d = dist[eg];
        float pos = d * INVSTEP;
        int kk = (int)pos;
        kk = (kk < 0) ? 0 : ((kk > 510) ? 510 : kk);
        kxv = kk * 256;
        ff = pos - (float)kk;
        // src = eg/767 (exact magic div), dst = r + (r>=src)
        unsigned i = (unsigned)(((unsigned long long)(unsigned)eg * 2867044662ull) >> 41);
        int r = eg - (int)i * 767;
        int jd = r + (r >= (int)i);
        fa = ha[i];
        fb = ha[jd];
    }
    const char* TTb2 = (const char*)TTro + c * 4;
    const float wa = row1[c], wb = row1[DIM + c];
    const int e2 = (c >> 1) & 15, p2 = c & 1, kh = c >> 5;
    const float bias2 = (kh == 0) ? rob2[p2] : 0.0f;
    float* sh = s_h[widx];
    #pragma unroll
    for (int ch = 0; ch < 4; ++ch) {
        #pragma unroll
        for (int half = 0; half < 2; ++half) {
            unsigned st[8];
            #pragma unroll
            for (int u = 0; u < 8; ++u) {            // stage: 8 independent row loads
                const int le = ch * 16 + half * 8 + u;
                int kxu = lane_bcast_i(kxv, le);
                st[u] = *(const unsigned*)(TTb2 + kxu);
            }
            #pragma unroll
            for (int u = 0; u < 8; ++u) {            // consume
                const int le = ch * 16 + half * 8 + u;
                const int e = half * 8 + u;
                float fu  = lane_bcast_f(ff, le);
                float fau = lane_bcast_f(fa, le);
                float fbu = lane_bcast_f(fb, le);
                float2 tt = pair2f(st[u]);
                float hv = fmaf(fu, tt.y - tt.x, tt.x);
                hv = fmaf(fau, wa, hv);
                hv = fmaf(fbu, wb, hv);
                sh[e * 65 + c] = fmaxf(hv, 0.0f);
            }
        }
        // lane = (khalf, edge, logit); half-k dot then combine
        float lsum = bias2;
        #pragma unroll 8
        for (int k8 = 0; k8 < 32; ++k8) {
            int k = kh * 32 + k8;
            lsum = fmaf(sh[e2 * 65 + k], s_w2[2 * k + p2], lsum);
        }
        lsum += __shfl_xor(lsum, 32, 64);
        float other = __shfl_xor(lsum, 1, 64);
        float m = fmaxf(lsum, other);
        float ea = __expf(lsum - m), eb = __expf(other - m);
        float r = ea / (ea + eb);
        if (c < 32) out[ebase * 2 + ch * 32 + c] = r;
    }
}

extern "C" void kernel_launch(void* const* d_in, const int* in_sizes, int n_in,
                              void* d_out, int out_size, void* d_ws, size_t ws_size,
                              hipStream_t stream) {
    const int*   types = (const int*)d_in[0];
    const float* dist  = (const float*)d_in[1];
    const float* emb   = (const float*)d_in[4];
    const float* w1    = (const float*)d_in[5];
    const float* pw1   = (const float*)d_in[6];
    const float* pb1   = (const float*)d_in[7];
    const float* pw2   = (const float*)d_in[8];
    const float* pb2   = (const float*)d_in[9];
    const float* qw1   = (const float*)d_in[10];
    const float* qb1   = (const float*)d_in[11];
    const float* qw2   = (const float*)d_in[12];
    const float* qb2   = (const float*)d_in[13];
    const float* auw1  = (const float*)d_in[14];
    const float* aub1  = (const float*)d_in[15];
    const float* auw2  = (const float*)d_in[16];
    const float* aub2  = (const float*)d_in[17];
    const float* row1  = (const float*)d_in[18];
    const float* rob1  = (const float*)d_in[19];
    const float* row2  = (const float*)d_in[20];
    const float* rob2  = (const float*)d_in[21];

    float* ws   = (float*)d_ws;
    float* outp = (float*)d_out;
    const __half*  TTC = (const __half*)(ws + WS_TTC);
    const __half2* TTR = (const __half2*)(ws + WS_TTR);
    __half* nwbuf[2] = { (__half*)(ws + WS_NWA), (__half*)(ws + WS_NWB) };

    k_pre<<<656, 256, 0, stream>>>(types, dist, emb, w1, pw1, pb1, pw2, pb2,
                                   row1, rob1, ws);
    for (int l = 0; l < 3; ++l) {
        k_edgeupd<<<768, 512, 0, stream>>>(TTC + l * (G2 * DIM),
            ws + WS_DISTT, nwbuf[l & 1],
            qw1 + l * DIM * DIM, qb1 + l * DIM,
            qw2 + l * DIM * DIM, qb2 + l * DIM,
            ws + WS_H,
            (l < 2) ? (w1 + (l + 1) * DIM * DIM) : w1, nwbuf[(l + 1) & 1],
            auw1, aub1, auw2, aub2, ws + WS_HA, (l == 2) ? 1 : 0);
    }
    k_ro<<<2301, 256, 0, stream>>>(dist, ws + WS_HA, TTR,
                                   row1, row2, rob2, outp);
}

// Round 12
// 180.270 us; speedup vs baseline: 1.1162x; 1.1162x over previous
//
#include <hip/hip_runtime.h>
#include <hip/hip_fp16.h>

#define NATOMS 768
#define NM1    767
#define NEDGE  (768*767)       // 589056
#define DIM    64
#define NC     50
#define GAPF   (5.0f/49.0f)
#define NIGAP  (-49.0f/5.0f)
#define G      512
#define STEPF  (5.0f/511.0f)
#define INVSTEP (511.0f/5.0f)
#define LN2F   0.693147180559945f

// ws layout (float offsets)
#define WS_H     0              // 768*64 f32
#define WS_NWA   49152          // 768*64 f16 ROW-MAJOR: nw[i*64+c]
#define WS_NWB   73728          // 768*64 f16 row-major
#define WS_HA    98304          // 768 f32 (+pad)
#define WS_DISTT 99328          // 768*768 f32
#define WS_TT    689152         // 4 tables * 512*64 __half2 = 131072 float slots

// Force all previously-issued loads' results live: loads cannot sink past a
// memory clobber, so stage/consume separation survives the scheduler and the
// compiler emits counted vmcnt waits instead of per-pair vmcnt(0).
#define PIPE_FENCE() asm volatile("" ::: "memory")

__device__ __forceinline__ float softplus05(float x) {
    float bx = 0.5f * x;
    return (bx > 14.0f) ? x : 2.0f * __logf(1.0f + __expf(bx));
}
__device__ __forceinline__ int lane_bcast_i(int v, int l) {
    return __builtin_amdgcn_readlane(v, l);
}
__device__ __forceinline__ float lane_bcast_f(float v, int l) {
    return __uint_as_float((unsigned)__builtin_amdgcn_readlane((int)__float_as_uint(v), l));
}
__device__ __forceinline__ float2 pair2f(unsigned p) {
    __half2 h = *reinterpret_cast<__half2*>(&p);
    return __half22float2(h);
}

// ============ prologue: f16 tables + embed/nw0(row-major f16) + dist transpose ====
__global__ __launch_bounds__(256)
void k_pre(const int* __restrict__ types, const float* __restrict__ dist,
           const float* __restrict__ emb, const float* __restrict__ w1all,
           const float* __restrict__ pw1, const float* __restrict__ pb1,
           const float* __restrict__ pw2, const float* __restrict__ pb2,
           const float* __restrict__ row1, const float* __restrict__ rob1,
           float* __restrict__ ws) {
    __shared__ float s_t[4 * 64];
    __shared__ float s_tile[64][65];
    const int tid = threadIdx.x, widx = tid >> 6, c = tid & 63;
    float*  h     = ws + WS_H;
    __half* nwh   = (__half*)(ws + WS_NWA);
    float*  distT = ws + WS_DISTT;
    __half* TTh   = (__half*)(ws + WS_TT);
    const int b = blockIdx.x;

    if (b < 512) {
        const int w = b * 4 + widx, tbl = w >> 9, g = w & 511;
        const float d = g * STEPF;
        float val;
        if (tbl < 3) {
            const float* W1 = pw1 + tbl * NC * DIM;
            float t1 = pb1[tbl * DIM + c];
            for (int k = 0; k < NC; ++k) {
                float x = d - GAPF * (float)k;
                t1 = fmaf(__expf(NIGAP * x * x), W1[k * DIM + c], t1);
            }
            s_t[widx * 64 + c] = softplus05(t1);     // wave-local lockstep
            const float* W2 = pw2 + tbl * DIM * DIM;
            val = pb2[tbl * DIM + c];
            #pragma unroll 8
            for (int k = 0; k < DIM; ++k)
                val = fmaf(s_t[widx * 64 + k], W2[k * DIM + c], val);
        } else {
            val = rob1[c];
            for (int k = 0; k < NC; ++k) {
                float x = d - GAPF * (float)k;
                val = fmaf(__expf(NIGAP * x * x), row1[(2 + k) * DIM + c], val);
            }
        }
        // paired f16 layout: entry (g,c) holds (T[g][c], T[g+1][c]) as __half2
        __half* TTt = TTh + tbl * (G * DIM * 2);
        TTt[(g * DIM + c) * 2] = __float2half(val);
        if (g > 0) TTt[((g - 1) * DIM + c) * 2 + 1] = __float2half(val);
    } else if (b < 704) {
        const int i = (b - 512) * 4 + widx;
        float hv = emb[types[i] * DIM + c];
        h[i * DIM + c] = hv;
        s_t[widx * 64 + c] = hv;                     // wave-local
        float acc = 0.0f;
        #pragma unroll 8
        for (int k = 0; k < DIM; ++k)
            acc = fmaf(s_t[widx * 64 + k], w1all[k * DIM + c], acc);
        nwh[i * 64 + c] = __float2half(acc);         // row-major
    } else {
        // ---- coalesced tiled transpose: dist(i-major, edge order) -> distT[j][i]
        const int t = b - 704;                       // 144 tiles = 12 x 12
        const int I0 = (t / 12) * 64, J0 = (t % 12) * 64;
        #pragma unroll 4
        for (int r = 0; r < 16; ++r) {               // read rows of dist, coalesced in j
            const int i = I0 + widx * 16 + r;
            const int j = J0 + c;
            s_tile[widx * 16 + r][c] =
                (i == j) ? 0.0f : dist[i * NM1 + (j - (j > i))];
        }
        __syncthreads();
        #pragma unroll 4
        for (int r = 0; r < 16; ++r) {               // write rows of distT, coalesced in i
            const int j = J0 + widx * 16 + r;
            const int i = I0 + c;
            distT[j * NATOMS + i] = s_tile[c][widx * 16 + r];
        }
    }
}

// ============ conv layer: channel-pair lanes + FENCED staged loads ============
// 768 blocks x 8 waves; wave widx covers sources [widx*96, widx*96+96).
// Lane c owns channels 2*(c&31), 2*(c&31)+1 of source-half (c>>5).
// PIPE_FENCE between stage and consume keeps 16 loads in flight per group.
__global__ __launch_bounds__(512)
void k_edgeupd(const __half2* __restrict__ TTl, const float* __restrict__ distT,
               const __half* __restrict__ nwin,
               const float* __restrict__ qw1, const float* __restrict__ qb1,
               const float* __restrict__ qw2, const float* __restrict__ qb2,
               float* __restrict__ h,
               const float* __restrict__ wnext, __half* __restrict__ nwout,
               const float* __restrict__ auw1, const float* __restrict__ aub1,
               const float* __restrict__ auw2, const float* __restrict__ aub2,
               float* __restrict__ ha, int last) {
    __shared__ float s_part[8][64];
    __shared__ float s_upd[192];
    const int tid = threadIdx.x, widx = tid >> 6, c = tid & 63;
    const int j = blockIdx.x;
    const int s0 = widx * 96;
    const int half = c >> 5, cl = c & 31;

    const char* TTrow = (const char*)TTl + cl * 8;   // lane's 2-channel slot in a row
    float2 csum = make_float2(0.0f, 0.0f);
    { // ---- chunk A: sources s0 .. s0+63 (32 pairs); lane c holds (g,f) of s0+c
        float d = distT[j * NATOMS + s0 + c];
        float pos = d * INVSTEP;
        int g = (int)pos;
        g = (g < 0) ? 0 : ((g > 510) ? 510 : g);
        float f = pos - (float)g;
        int kx = g * 256;                            // byte offset of f16 row
        const char* nwrow = (const char*)nwin + s0 * 128 + half * 128 + cl * 4;
        for (int grp = 0; grp < 4; ++grp) {          // 4 groups of 8 pairs
            uint2 st[8]; unsigned sn[8];
            #pragma unroll
            for (int u = 0; u < 8; ++u) {            // stage: 16 independent loads
                const int t = grp * 8 + u;
                int kx0 = lane_bcast_i(kx, 2 * t);
                int kx1 = lane_bcast_i(kx, 2 * t + 1);
                int kxs = half ? kx1 : kx0;
                st[u] = *(const uint2*)(TTrow + kxs);
                sn[u] = *(const unsigned*)(nwrow + t * 256);
            }
            PIPE_FENCE();                            // keep all 16 loads in flight
            #pragma unroll
            for (int u = 0; u < 8; ++u) {            // consume
                const int t = grp * 8 + u;
                float f0 = lane_bcast_f(f, 2 * t);
                float f1 = lane_bcast_f(f, 2 * t + 1);
                float fs = half ? f1 : f0;
                float2 ta = pair2f(st[u].x);         // (T[g][ch0], T[g+1][ch0])
                float2 tb = pair2f(st[u].y);         // (T[g][ch1], T[g+1][ch1])
                float2 nwf = pair2f(sn[u]);          // (nw[s][ch0], nw[s][ch1])
                float e0 = fmaf(fs, ta.y - ta.x, ta.x);
                float e1 = fmaf(fs, tb.y - tb.x, tb.x);
                csum.x = fmaf(e0, nwf.x, csum.x);
                csum.y = fmaf(e1, nwf.y, csum.y);
            }
        }
    }
    { // ---- chunk B: sources s0+64 .. s0+95 (16 pairs); lanes mirrored via c&31
        float d = distT[j * NATOMS + s0 + 64 + cl];
        float pos = d * INVSTEP;
        int g = (int)pos;
        g = (g < 0) ? 0 : ((g > 510) ? 510 : g);
        float f = pos - (float)g;
        int kx = g * 256;
        const char* nwrow = (const char*)nwin + (s0 + 64) * 128 + half * 128 + cl * 4;
        for (int grp = 0; grp < 2; ++grp) {          // 2 groups of 8 pairs
            uint2 st[8]; unsigned sn[8];
            #pragma unroll
            for (int u = 0; u < 8; ++u) {
                const int t = grp * 8 + u;
                int kx0 = lane_bcast_i(kx, 2 * t);
                int kx1 = lane_bcast_i(kx, 2 * t + 1);
                int kxs = half ? kx1 : kx0;
                st[u] = *(const uint2*)(TTrow + kxs);
                sn[u] = *(const unsigned*)(nwrow + t * 256);
            }
            PIPE_FENCE();
            #pragma unroll
            for (int u = 0; u < 8; ++u) {
                const int t = grp * 8 + u;
                float f0 = lane_bcast_f(f, 2 * t);
                float f1 = lane_bcast_f(f, 2 * t + 1);
                float fs = half ? f1 : f0;
                float2 ta = pair2f(st[u].x);
                float2 tb = pair2f(st[u].y);
                float2 nwf = pair2f(sn[u]);
                float e0 = fmaf(fs, ta.y - ta.x, ta.x);
                float e1 = fmaf(fs, tb.y - tb.x, tb.x);
                csum.x = fmaf(e0, nwf.x, csum.x);
                csum.y = fmaf(e1, nwf.y, csum.y);
            }
        }
    }
    // combine even/odd source halves and repack to channel-per-slot
    float2 tot2;
    tot2.x = csum.x + __shfl_xor(csum.x, 32, 64);
    tot2.y = csum.y + __shfl_xor(csum.y, 32, 64);
    if (half == 0) *(float2*)&s_part[widx][2 * cl] = tot2;
    __syncthreads();

    if (widx == 0) {
        float tot = 0.0f;
        #pragma unroll
        for (int w8 = 0; w8 < 8; ++w8) tot += s_part[w8][c];
        // remove fake i==j term: distT diag=0 -> g=0,f=0 -> e = T[0][c] exactly
        float2 t0 = pair2f(((const unsigned*)TTl)[c]);
        float nwj = __half2float(nwin[j * 64 + c]);
        tot -= t0.x * nwj;
        // node MLP (wave-local LDS, lockstep)
        s_upd[c] = tot;
        float t = qb1[c];
        #pragma unroll 8
        for (int k = 0; k < DIM; ++k) t = fmaf(s_upd[k], qw1[k * DIM + c], t);
        s_upd[64 + c] = softplus05(t);
        float o = qb2[c];
        #pragma unroll 8
        for (int k = 0; k < DIM; ++k) o = fmaf(s_upd[64 + k], qw2[k * DIM + c], o);
        float hn = h[j * DIM + c] + o;
        h[j * DIM + c] = hn;
        s_upd[128 + c] = hn;
        if (!last) {
            float v = 0.0f;
            #pragma unroll 8
            for (int k = 0; k < DIM; ++k) v = fmaf(s_upd[128 + k], wnext[k * DIM + c], v);
            nwout[j * 64 + c] = __float2half(v);     // row-major
        } else {
            float t2 = aub1[c];
            #pragma unroll 8
            for (int k = 0; k < DIM; ++k) t2 = fmaf(s_upd[128 + k], auw1[k * DIM + c], t2);
            t2 = ((t2 > 20.0f) ? t2 : __logf(1.0f + __expf(t2))) - LN2F;
            float v = t2 * auw2[c];
            #pragma unroll
            for (int s = 32; s > 0; s >>= 1) v += __shfl_down(v, s, 64);
            if (c == 0) ha[j] = v + aub2[0];
        }
    }
}

// ============ readout: FENCED staged loads; src/dst by exact magic division ====
__global__ __launch_bounds__(256)
void k_ro(const float* __restrict__ dist, const float* __restrict__ ha,
          const __half2* __restrict__ TTro,
          const float* __restrict__ row1, const float* __restrict__ row2,
          const float* __restrict__ rob2, float* __restrict__ out) {
    __shared__ float s_h[4][16 * 65];
    __shared__ float s_w2[128];
    const int tid = threadIdx.x, widx = tid >> 6, c = tid & 63;
    if (tid < 128) s_w2[tid] = row2[tid];
    __syncthreads();
    const int ebase = (blockIdx.x * 4 + widx) * 64;

    // lane c holds the params of edge ebase+c, in registers
    int kxv; float ff, fa, fb;
    {
        int eg = ebase + c;
        float d = dist[eg];
        float pos = d * INVSTEP;
        int kk = (int)pos;
        kk = (kk < 0) ? 0 : ((kk > 510) ? 510 : kk);
        kxv = kk * 256;
        ff = pos - (float)kk;
        // src = eg/767 (exact magic div), dst = r + (r>=src)
        unsigned i = (unsigned)(((unsigned long long)(unsigned)eg * 2867044662ull) >> 41);
        int r = eg - (int)i * 767;
        int jd = r + (r >= (int)i);
        fa = ha[i];
        fb = ha[jd];
    }
    const char* TTb2 = (const char*)TTro + c * 4;
    const float wa = row1[c], wb = row1[DIM + c];
    const int e2 = (c >> 1) & 15, p2 = c & 1, kh = c >> 5;
    const float bias2 = (kh == 0) ? rob2[p2] : 0.0f;
    float* sh = s_h[widx];
    #pragma unroll
    for (int ch = 0; ch < 4; ++ch) {
        #pragma unroll
        for (int half = 0; half < 2; ++half) {
            unsigned st[8];
            #pragma unroll
            for (int u = 0; u < 8; ++u) {            // stage: 8 independent row loads
                const int le = ch * 16 + half * 8 + u;
                int kxu = lane_bcast_i(kxv, le);
                st[u] = *(const unsigned*)(TTb2 + kxu);
            }
            PIPE_FENCE();                            // keep all 8 loads in flight
            #pragma unroll
            for (int u = 0; u < 8; ++u) {            // consume
                const int le = ch * 16 + half * 8 + u;
                const int e = half * 8 + u;
                float fu  = lane_bcast_f(ff, le);
                float fau = lane_bcast_f(fa, le);
                float fbu = lane_bcast_f(fb, le);
                float2 tt = pair2f(st[u]);
                float hv = fmaf(fu, tt.y - tt.x, tt.x);
                hv = fmaf(fau, wa, hv);
                hv = fmaf(fbu, wb, hv);
                sh[e * 65 + c] = fmaxf(hv, 0.0f);
            }
        }
        // lane = (khalf, edge, logit); half-k dot then combine
        float lsum = bias2;
        #pragma unroll 8
        for (int k8 = 0; k8 < 32; ++k8) {
            int k = kh * 32 + k8;
            lsum = fmaf(sh[e2 * 65 + k], s_w2[2 * k + p2], lsum);
        }
        lsum += __shfl_xor(lsum, 32, 64);
        float other = __shfl_xor(lsum, 1, 64);
        float m = fmaxf(lsum, other);
        float ea = __expf(lsum - m), eb = __expf(other - m);
        float r = ea / (ea + eb);
        if (c < 32) out[ebase * 2 + ch * 32 + c] = r;
    }
}

extern "C" void kernel_launch(void* const* d_in, const int* in_sizes, int n_in,
                              void* d_out, int out_size, void* d_ws, size_t ws_size,
                              hipStream_t stream) {
    const int*   types = (const int*)d_in[0];
    const float* dist  = (const float*)d_in[1];
    const float* emb   = (const float*)d_in[4];
    const float* w1    = (const float*)d_in[5];
    const float* pw1   = (const float*)d_in[6];
    const float* pb1   = (const float*)d_in[7];
    const float* pw2   = (const float*)d_in[8];
    const float* pb2   = (const float*)d_in[9];
    const float* qw1   = (const float*)d_in[10];
    const float* qb1   = (const float*)d_in[11];
    const float* qw2   = (const float*)d_in[12];
    const float* qb2   = (const float*)d_in[13];
    const float* auw1  = (const float*)d_in[14];
    const float* aub1  = (const float*)d_in[15];
    const float* auw2  = (const float*)d_in[16];
    const float* aub2  = (const float*)d_in[17];
    const float* row1  = (const float*)d_in[18];
    const float* rob1  = (const float*)d_in[19];
    const float* row2  = (const float*)d_in[20];
    const float* rob2  = (const float*)d_in[21];

    float* ws   = (float*)d_ws;
    float* outp = (float*)d_out;
    const __half2* TT = (const __half2*)(ws + WS_TT);
    __half* nwbuf[2] = { (__half*)(ws + WS_NWA), (__half*)(ws + WS_NWB) };

    k_pre<<<848, 256, 0, stream>>>(types, dist, emb, w1, pw1, pb1, pw2, pb2,
                                   row1, rob1, ws);
    for (int l = 0; l < 3; ++l) {
        k_edgeupd<<<768, 512, 0, stream>>>(TT + l * (G * DIM),
            ws + WS_DISTT, nwbuf[l & 1],
            qw1 + l * DIM * DIM, qb1 + l * DIM,
            qw2 + l * DIM * DIM, qb2 + l * DIM,
            ws + WS_H,
            (l < 2) ? (w1 + (l + 1) * DIM * DIM) : w1, nwbuf[(l + 1) & 1],
            auw1, aub1, auw2, aub2, ws + WS_HA, (l == 2) ? 1 : 0);
    }
    k_ro<<<2301, 256, 0, stream>>>(dist, ws + WS_HA, TT + 3 * (G * DIM),
                                   row1, row2, rob2, outp);
}

// Round 13
// 171.984 us; speedup vs baseline: 1.1700x; 1.0482x over previous
//
#include <hip/hip_runtime.h>
#include <hip/hip_fp16.h>

#define NATOMS 768
#define NM1    767
#define NEDGE  (768*767)       // 589056
#define DIM    64
#define NC     50
#define GAPF   (5.0f/49.0f)
#define NIGAP  (-49.0f/5.0f)
#define G      512
#define STEPF  (5.0f/511.0f)
#define INVSTEP (511.0f/5.0f)
#define LN2F   0.693147180559945f

// ws layout (float offsets)
#define WS_H     0              // 768*64 f32
#define WS_NWA   49152          // 768*64 f16 ROW-MAJOR: nw[i*64+c]
#define WS_NWB   73728          // 768*64 f16 row-major
#define WS_HA    98304          // 768 f32 (+pad)
#define WS_DISTT 99328          // 768*768 f32
#define WS_TT    689152         // 4 tables * 512*64 __half2 = 131072 float slots

#define PIPE_FENCE() asm volatile("" ::: "memory")

__device__ __forceinline__ float softplus05(float x) {
    float bx = 0.5f * x;
    return (bx > 14.0f) ? x : 2.0f * __logf(1.0f + __expf(bx));
}
__device__ __forceinline__ int lane_bcast_i(int v, int l) {
    return __builtin_amdgcn_readlane(v, l);
}
__device__ __forceinline__ float lane_bcast_f(float v, int l) {
    return __uint_as_float((unsigned)__builtin_amdgcn_readlane((int)__float_as_uint(v), l));
}
__device__ __forceinline__ float2 pair2f(unsigned p) {
    __half2 h = *reinterpret_cast<__half2*>(&p);
    return __half22float2(h);
}

// ============ prologue: f16 tables + embed/nw0(row-major f16) + dist transpose ====
__global__ __launch_bounds__(256)
void k_pre(const int* __restrict__ types, const float* __restrict__ dist,
           const float* __restrict__ emb, const float* __restrict__ w1all,
           const float* __restrict__ pw1, const float* __restrict__ pb1,
           const float* __restrict__ pw2, const float* __restrict__ pb2,
           const float* __restrict__ row1, const float* __restrict__ rob1,
           float* __restrict__ ws) {
    __shared__ float s_t[4 * 64];
    __shared__ float s_tile[64][65];
    const int tid = threadIdx.x, widx = tid >> 6, c = tid & 63;
    float*  h     = ws + WS_H;
    __half* nwh   = (__half*)(ws + WS_NWA);
    float*  distT = ws + WS_DISTT;
    __half* TTh   = (__half*)(ws + WS_TT);
    const int b = blockIdx.x;

    if (b < 512) {
        const int w = b * 4 + widx, tbl = w >> 9, g = w & 511;
        const float d = g * STEPF;
        float val;
        if (tbl < 3) {
            const float* W1 = pw1 + tbl * NC * DIM;
            float t1 = pb1[tbl * DIM + c];
            for (int k = 0; k < NC; ++k) {
                float x = d - GAPF * (float)k;
                t1 = fmaf(__expf(NIGAP * x * x), W1[k * DIM + c], t1);
            }
            s_t[widx * 64 + c] = softplus05(t1);     // wave-local lockstep
            const float* W2 = pw2 + tbl * DIM * DIM;
            val = pb2[tbl * DIM + c];
            #pragma unroll 8
            for (int k = 0; k < DIM; ++k)
                val = fmaf(s_t[widx * 64 + k], W2[k * DIM + c], val);
        } else {
            val = rob1[c];
            for (int k = 0; k < NC; ++k) {
                float x = d - GAPF * (float)k;
                val = fmaf(__expf(NIGAP * x * x), row1[(2 + k) * DIM + c], val);
            }
        }
        // paired f16 layout: entry (g,c) holds (T[g][c], T[g+1][c]) as __half2
        __half* TTt = TTh + tbl * (G * DIM * 2);
        TTt[(g * DIM + c) * 2] = __float2half(val);
        if (g > 0) TTt[((g - 1) * DIM + c) * 2 + 1] = __float2half(val);
    } else if (b < 704) {
        const int i = (b - 512) * 4 + widx;
        float hv = emb[types[i] * DIM + c];
        h[i * DIM + c] = hv;
        s_t[widx * 64 + c] = hv;                     // wave-local
        float acc = 0.0f;
        #pragma unroll 8
        for (int k = 0; k < DIM; ++k)
            acc = fmaf(s_t[widx * 64 + k], w1all[k * DIM + c], acc);
        nwh[i * 64 + c] = __float2half(acc);         // row-major
    } else {
        // ---- coalesced tiled transpose: dist(i-major, edge order) -> distT[j][i]
        const int t = b - 704;                       // 144 tiles = 12 x 12
        const int I0 = (t / 12) * 64, J0 = (t % 12) * 64;
        #pragma unroll 4
        for (int r = 0; r < 16; ++r) {               // read rows of dist, coalesced in j
            const int i = I0 + widx * 16 + r;
            const int j = J0 + c;
            s_tile[widx * 16 + r][c] =
                (i == j) ? 0.0f : dist[i * NM1 + (j - (j > i))];
        }
        __syncthreads();
        #pragma unroll 4
        for (int r = 0; r < 16; ++r) {               // write rows of distT, coalesced in i
            const int j = J0 + widx * 16 + r;
            const int i = I0 + c;
            distT[j * NATOMS + i] = s_tile[c][widx * 16 + r];
        }
    }
}

// ============ conv layer: R12 edge loop + PARALLEL-K tail across 8 waves =======
// 768 blocks x 8 waves; wave widx covers sources [widx*96, widx*96+96).
// Tail MLPs: wave widx computes k-slice [widx*8, widx*8+8) partials; wave 0
// combines.  Replaces the old 64-deep single-wave lockstep chains (~3 us/blk).
__global__ __launch_bounds__(512)
void k_edgeupd(const __half2* __restrict__ TTl, const float* __restrict__ distT,
               const __half* __restrict__ nwin,
               const float* __restrict__ qw1, const float* __restrict__ qb1,
               const float* __restrict__ qw2, const float* __restrict__ qb2,
               float* __restrict__ h,
               const float* __restrict__ wnext, __half* __restrict__ nwout,
               const float* __restrict__ auw1, const float* __restrict__ aub1,
               const float* __restrict__ auw2, const float* __restrict__ aub2,
               float* __restrict__ ha, int last) {
    __shared__ float s_part[8][64];                  // edge partials, then k-partials
    __shared__ float s_upd[192];
    const int tid = threadIdx.x, widx = tid >> 6, c = tid & 63;
    const int j = blockIdx.x;
    const int s0 = widx * 96;
    const int half = c >> 5, cl = c & 31;

    // prefetch wave-0 tail operands early (uniform across waves, L1 broadcast)
    float2 t0_pf = pair2f(((const unsigned*)TTl)[c]);
    float nwj_pf = __half2float(nwin[j * 64 + c]);
    float hj_pf  = h[j * DIM + c];

    const char* TTrow = (const char*)TTl + cl * 8;   // lane's 2-channel slot in a row
    float2 csum = make_float2(0.0f, 0.0f);
    { // ---- chunk A: sources s0 .. s0+63 (32 pairs); lane c holds (g,f) of s0+c
        float d = distT[j * NATOMS + s0 + c];
        float pos = d * INVSTEP;
        int g = (int)pos;
        g = (g < 0) ? 0 : ((g > 510) ? 510 : g);
        float f = pos - (float)g;
        int kx = g * 256;                            // byte offset of f16 row
        const char* nwrow = (const char*)nwin + s0 * 128 + half * 128 + cl * 4;
        for (int grp = 0; grp < 4; ++grp) {          // 4 groups of 8 pairs
            uint2 st[8]; unsigned sn[8];
            #pragma unroll
            for (int u = 0; u < 8; ++u) {            // stage: 16 independent loads
                const int t = grp * 8 + u;
                int kx0 = lane_bcast_i(kx, 2 * t);
                int kx1 = lane_bcast_i(kx, 2 * t + 1);
                int kxs = half ? kx1 : kx0;
                st[u] = *(const uint2*)(TTrow + kxs);
                sn[u] = *(const unsigned*)(nwrow + t * 256);
            }
            PIPE_FENCE();
            #pragma unroll
            for (int u = 0; u < 8; ++u) {            // consume
                const int t = grp * 8 + u;
                float f0 = lane_bcast_f(f, 2 * t);
                float f1 = lane_bcast_f(f, 2 * t + 1);
                float fs = half ? f1 : f0;
                float2 ta = pair2f(st[u].x);
                float2 tb = pair2f(st[u].y);
                float2 nwf = pair2f(sn[u]);
                float e0 = fmaf(fs, ta.y - ta.x, ta.x);
                float e1 = fmaf(fs, tb.y - tb.x, tb.x);
                csum.x = fmaf(e0, nwf.x, csum.x);
                csum.y = fmaf(e1, nwf.y, csum.y);
            }
        }
    }
    { // ---- chunk B: sources s0+64 .. s0+95 (16 pairs); lanes mirrored via c&31
        float d = distT[j * NATOMS + s0 + 64 + cl];
        float pos = d * INVSTEP;
        int g = (int)pos;
        g = (g < 0) ? 0 : ((g > 510) ? 510 : g);
        float f = pos - (float)g;
        int kx = g * 256;
        const char* nwrow = (const char*)nwin + (s0 + 64) * 128 + half * 128 + cl * 4;
        for (int grp = 0; grp < 2; ++grp) {          // 2 groups of 8 pairs
            uint2 st[8]; unsigned sn[8];
            #pragma unroll
            for (int u = 0; u < 8; ++u) {
                const int t = grp * 8 + u;
                int kx0 = lane_bcast_i(kx, 2 * t);
                int kx1 = lane_bcast_i(kx, 2 * t + 1);
                int kxs = half ? kx1 : kx0;
                st[u] = *(const uint2*)(TTrow + kxs);
                sn[u] = *(const unsigned*)(nwrow + t * 256);
            }
            PIPE_FENCE();
            #pragma unroll
            for (int u = 0; u < 8; ++u) {
                const int t = grp * 8 + u;
                float f0 = lane_bcast_f(f, 2 * t);
                float f1 = lane_bcast_f(f, 2 * t + 1);
                float fs = half ? f1 : f0;
                float2 ta = pair2f(st[u].x);
                float2 tb = pair2f(st[u].y);
                float2 nwf = pair2f(sn[u]);
                float e0 = fmaf(fs, ta.y - ta.x, ta.x);
                float e1 = fmaf(fs, tb.y - tb.x, tb.x);
                csum.x = fmaf(e0, nwf.x, csum.x);
                csum.y = fmaf(e1, nwf.y, csum.y);
            }
        }
    }
    // combine even/odd source halves and repack to channel-per-slot
    float2 tot2;
    tot2.x = csum.x + __shfl_xor(csum.x, 32, 64);
    tot2.y = csum.y + __shfl_xor(csum.y, 32, 64);
    if (half == 0) *(float2*)&s_part[widx][2 * cl] = tot2;
    __syncthreads();

    // ---- stage A: combine edge partials + diag fix (wave 0) -> s_upd[0..63]
    if (widx == 0) {
        float tot = 0.0f;
        #pragma unroll
        for (int w8 = 0; w8 < 8; ++w8) tot += s_part[w8][c];
        tot -= t0_pf.x * nwj_pf;     // remove fake i==j term (e = T[0][c] exactly)
        s_upd[c] = tot;
    }
    __syncthreads();
    // ---- stage B: MLP1 parallel-k (all 8 waves), combine + softplus (wave 0)
    {
        const int k0 = widx * 8;
        float p = 0.0f;
        #pragma unroll
        for (int u = 0; u < 8; ++u)
            p = fmaf(s_upd[k0 + u], qw1[(k0 + u) * DIM + c], p);
        s_part[widx][c] = p;
    }
    __syncthreads();
    if (widx == 0) {
        float t = qb1[c];
        #pragma unroll
        for (int w8 = 0; w8 < 8; ++w8) t += s_part[w8][c];
        s_upd[64 + c] = softplus05(t);
    }
    __syncthreads();
    // ---- stage C: MLP2 parallel-k, combine + h update (wave 0)
    {
        const int k0 = widx * 8;
        float p = 0.0f;
        #pragma unroll
        for (int u = 0; u < 8; ++u)
            p = fmaf(s_upd[64 + k0 + u], qw2[(k0 + u) * DIM + c], p);
        s_part[widx][c] = p;
    }
    __syncthreads();
    if (widx == 0) {
        float o = qb2[c];
        #pragma unroll
        for (int w8 = 0; w8 < 8; ++w8) o += s_part[w8][c];
        float hn = hj_pf + o;
        h[j * DIM + c] = hn;
        s_upd[128 + c] = hn;
    }
    __syncthreads();
    // ---- stage D: next-layer nw (or atom-update head) parallel-k
    {
        const int k0 = widx * 8;
        const float* W = last ? auw1 : wnext;
        float p = 0.0f;
        #pragma unroll
        for (int u = 0; u < 8; ++u)
            p = fmaf(s_upd[128 + k0 + u], W[(k0 + u) * DIM + c], p);
        s_part[widx][c] = p;
    }
    __syncthreads();
    if (widx == 0) {
        if (!last) {
            float v = 0.0f;
            #pragma unroll
            for (int w8 = 0; w8 < 8; ++w8) v += s_part[w8][c];
            nwout[j * 64 + c] = __float2half(v);     // row-major
        } else {
            float t2 = aub1[c];
            #pragma unroll
            for (int w8 = 0; w8 < 8; ++w8) t2 += s_part[w8][c];
            t2 = ((t2 > 20.0f) ? t2 : __logf(1.0f + __expf(t2))) - LN2F;
            float v = t2 * auw2[c];
            #pragma unroll
            for (int s = 32; s > 0; s >>= 1) v += __shfl_down(v, s, 64);
            if (c == 0) ha[j] = v + aub2[0];
        }
    }
}

// ============ readout: FENCED staged loads; src/dst by exact magic division ====
__global__ __launch_bounds__(256)
void k_ro(const float* __restrict__ dist, const float* __restrict__ ha,
          const __half2* __restrict__ TTro,
          const float* __restrict__ row1, const float* __restrict__ row2,
          const float* __restrict__ rob2, float* __restrict__ out) {
    __shared__ float s_h[4][16 * 65];
    __shared__ float s_w2[128];
    const int tid = threadIdx.x, widx = tid >> 6, c = tid & 63;
    if (tid < 128) s_w2[tid] = row2[tid];
    __syncthreads();
    const int ebase = (blockIdx.x * 4 + widx) * 64;

    // lane c holds the params of edge ebase+c, in registers
    int kxv; float ff, fa, fb;
    {
        int eg = ebase + c;
        float d = dist[eg];
        float pos = d * INVSTEP;
        int kk = (int)pos;
        kk = (kk < 0) ? 0 : ((kk > 510) ? 510 : kk);
        kxv = kk * 256;
        ff = pos - (float)kk;
        // src = eg/767 (exact magic div), dst = r + (r>=src)
        unsigned i = (unsigned)(((unsigned long long)(unsigned)eg * 2867044662ull) >> 41);
        int r = eg - (int)i * 767;
        int jd = r + (r >= (int)i);
        fa = ha[i];
        fb = ha[jd];
    }
    const char* TTb2 = (const char*)TTro + c * 4;
    const float wa = row1[c], wb = row1[DIM + c];
    const int e2 = (c >> 1) & 15, p2 = c & 1, kh = c >> 5;
    const float bias2 = (kh == 0) ? rob2[p2] : 0.0f;
    float* sh = s_h[widx];
    #pragma unroll
    for (int ch = 0; ch < 4; ++ch) {
        #pragma unroll
        for (int half = 0; half < 2; ++half) {
            unsigned st[8];
            #pragma unroll
            for (int u = 0; u < 8; ++u) {            // stage: 8 independent row loads
                const int le = ch * 16 + half * 8 + u;
                int kxu = lane_bcast_i(kxv, le);
                st[u] = *(const unsigned*)(TTb2 + kxu);
            }
            PIPE_FENCE();
            #pragma unroll
            for (int u = 0; u < 8; ++u) {            // consume
                const int le = ch * 16 + half * 8 + u;
                const int e = half * 8 + u;
                float fu  = lane_bcast_f(ff, le);
                float fau = lane_bcast_f(fa, le);
                float fbu = lane_bcast_f(fb, le);
                float2 tt = pair2f(st[u]);
                float hv = fmaf(fu, tt.y - tt.x, tt.x);
                hv = fmaf(fau, wa, hv);
                hv = fmaf(fbu, wb, hv);
                sh[e * 65 + c] = fmaxf(hv, 0.0f);
            }
        }
        // lane = (khalf, edge, logit); half-k dot then combine
        float lsum = bias2;
        #pragma unroll 8
        for (int k8 = 0; k8 < 32; ++k8) {
            int k = kh * 32 + k8;
            lsum = fmaf(sh[e2 * 65 + k], s_w2[2 * k + p2], lsum);
        }
        lsum += __shfl_xor(lsum, 32, 64);
        float other = __shfl_xor(lsum, 1, 64);
        float m = fmaxf(lsum, other);
        float ea = __expf(lsum - m), eb = __expf(other - m);
        float r = ea / (ea + eb);
        if (c < 32) out[ebase * 2 + ch * 32 + c] = r;
    }
}

extern "C" void kernel_launch(void* const* d_in, const int* in_sizes, int n_in,
                              void* d_out, int out_size, void* d_ws, size_t ws_size,
                              hipStream_t stream) {
    const int*   types = (const int*)d_in[0];
    const float* dist  = (const float*)d_in[1];
    const float* emb   = (const float*)d_in[4];
    const float* w1    = (const float*)d_in[5];
    const float* pw1   = (const float*)d_in[6];
    const float* pb1   = (const float*)d_in[7];
    const float* pw2   = (const float*)d_in[8];
    const float* pb2   = (const float*)d_in[9];
    const float* qw1   = (const float*)d_in[10];
    const float* qb1   = (const float*)d_in[11];
    const float* qw2   = (const float*)d_in[12];
    const float* qb2   = (const float*)d_in[13];
    const float* auw1  = (const float*)d_in[14];
    const float* aub1  = (const float*)d_in[15];
    const float* auw2  = (const float*)d_in[16];
    const float* aub2  = (const float*)d_in[17];
    const float* row1  = (const float*)d_in[18];
    const float* rob1  = (const float*)d_in[19];
    const float* row2  = (const float*)d_in[20];
    const float* rob2  = (const float*)d_in[21];

    float* ws   = (float*)d_ws;
    float* outp = (float*)d_out;
    const __half2* TT = (const __half2*)(ws + WS_TT);
    __half* nwbuf[2] = { (__half*)(ws + WS_NWA), (__half*)(ws + WS_NWB) };

    k_pre<<<848, 256, 0, stream>>>(types, dist, emb, w1, pw1, pb1, pw2, pb2,
                                   row1, rob1, ws);
    for (int l = 0; l < 3; ++l) {
        k_edgeupd<<<768, 512, 0, stream>>>(TT + l * (G * DIM),
            ws + WS_DISTT, nwbuf[l & 1],
            qw1 + l * DIM * DIM, qb1 + l * DIM,
            qw2 + l * DIM * DIM, qb2 + l * DIM,
            ws + WS_H,
            (l < 2) ? (w1 + (l + 1) * DIM * DIM) : w1, nwbuf[(l + 1) & 1],
            auw1, aub1, auw2, aub2, ws + WS_HA, (l == 2) ? 1 : 0);
    }
    k_ro<<<2301, 256, 0, stream>>>(dist, ws + WS_HA, TT + 3 * (G * DIM),
                                   row1, row2, rob2, outp);
}